// Round 1
// baseline (102.770 us; speedup 1.0000x reference)
//
#include <hip/hip_runtime.h>

// ALNN layer: B=64, K=13, L=200, D=64, fp32.
// out[b,k,d] = relu( sum_l w_v[k,l,d]*lat[b,k,l,d] + 200*b_v[k,d] )
// lat[b,k,l,d] = relu( wt0*x + wt1*dt + wt2*intensity + wt3*m + 4*b_t[k,l,d] )
// intensity = relu( x * exp(-relu(alpha[k]) * |t - 4k|) )

#define NB 64
#define NK 13
#define NL 200
#define ND 64

__global__ __launch_bounds__(256) void alnn_kernel(
    const float* __restrict__ X, const float* __restrict__ T,
    const float* __restrict__ M, const float* __restrict__ DT,
    const float* __restrict__ alpha, const float* __restrict__ w_v,
    const float* __restrict__ w_t, const float* __restrict__ b_v,
    const float* __restrict__ b_t, float* __restrict__ out)
{
    const int bk = blockIdx.x;
    const int b = bk / NK;
    const int k = bk % NK;
    const int tid = threadIdx.x;
    const int d  = tid & 63;   // feature lane
    const int lg = tid >> 6;   // l-slice 0..3

    const float a    = fmaxf(alpha[k], 0.0f);
    const float reft = 4.0f * (float)k;   // linspace(0,48,13) step = 4

    float acc = 0.0f;
    #pragma unroll 2
    for (int l = lg; l < NL; l += 4) {
        const int idx_in = (b * NL + l) * ND + d;
        const int idx_w  = (k * NL + l) * ND + d;
        const float x  = X[idx_in];
        const float t  = T[idx_in];
        const float m  = M[idx_in];
        const float dt = DT[idx_in];
        const float4 wt = ((const float4*)w_t)[idx_w];
        const float bt  = b_t[idx_w];
        const float wv  = w_v[idx_w];

        const float dist  = fabsf(t - reft);
        const float kern  = __expf(-a * dist);
        const float inten = fmaxf(x * kern, 0.0f);
        float s = wt.x * x + wt.y * dt + wt.z * inten + wt.w * m + 4.0f * bt;
        const float lat = fmaxf(s, 0.0f);
        acc = fmaf(wv, lat, acc);
    }

    __shared__ float red[4][64];
    red[lg][d] = acc;
    __syncthreads();
    if (lg == 0) {
        float s = red[0][d] + red[1][d] + red[2][d] + red[3][d];
        s += (float)NL * b_v[k * ND + d];
        out[(b * NK + k) * ND + d] = fmaxf(s, 0.0f);
    }
}

extern "C" void kernel_launch(void* const* d_in, const int* in_sizes, int n_in,
                              void* d_out, int out_size, void* d_ws, size_t ws_size,
                              hipStream_t stream) {
    const float* X     = (const float*)d_in[0];
    const float* T     = (const float*)d_in[1];
    const float* M     = (const float*)d_in[2];
    const float* DT    = (const float*)d_in[3];
    const float* alpha = (const float*)d_in[4];
    const float* w_v   = (const float*)d_in[5];
    const float* w_t   = (const float*)d_in[6];
    const float* b_v   = (const float*)d_in[7];
    const float* b_t   = (const float*)d_in[8];
    float* out = (float*)d_out;

    alnn_kernel<<<NB * NK, 256, 0, stream>>>(X, T, M, DT, alpha, w_v, w_t, b_v, b_t, out);
}